// Round 1
// baseline (90.645 us; speedup 1.0000x reference)
//
#include <hip/hip_runtime.h>
#include <hip/hip_bf16.h>

// out[i][j] = (j < pos[i]) ? images[i][j] : 0
// N = 16384 rows, L = 4096 cols, fp32.
// One thread per float4. L/4 = 1024 float4 per row (power of 2 -> shifts).

#define LOG2_C4 10   // log2(L/4) = log2(1024)

__global__ __launch_bounds__(256)
void ControlFlowScanDecomposition_151564_46308337386065_kernel(
        const float4* __restrict__ img,
        const int*    __restrict__ pos,
        float4*       __restrict__ out) {
    const int idx = blockIdx.x * blockDim.x + threadIdx.x;   // 0 .. N*1024-1
    const int row = idx >> LOG2_C4;
    const int c4  = idx & ((1 << LOG2_C4) - 1);
    const int p   = pos[row];          // wave-uniform (16 waves/row), L2/L1 cached
    const int j0  = c4 << 2;           // first element index of this float4

    float4 v;
    if (j0 + 4 <= p) {
        // fully inside the kept prefix: straight copy
        v = img[idx];
    } else if (j0 >= p) {
        // fully masked: write zeros, skip the load entirely
        v = make_float4(0.f, 0.f, 0.f, 0.f);
    } else {
        // straddle: load then zero the tail elements
        v = img[idx];
        if (j0 + 1 > p) v.y = 0.f;     // element j0+1 kept iff j0+1 < p
        if (j0 + 2 > p - 1) v.z = 0.f; // simpler: recompute below
        // (rewrite cleanly)
        v.x = (j0 + 0 < p) ? v.x : 0.f;
        v.y = (j0 + 1 < p) ? v.y : 0.f;
        v.z = (j0 + 2 < p) ? v.z : 0.f;
        v.w = (j0 + 3 < p) ? v.w : 0.f;
    }
    out[idx] = v;
}

extern "C" void kernel_launch(void* const* d_in, const int* in_sizes, int n_in,
                              void* d_out, int out_size, void* d_ws, size_t ws_size,
                              hipStream_t stream) {
    const float4* img = (const float4*)d_in[0];
    const int*    pos = (const int*)d_in[1];
    float4*       out = (float4*)d_out;

    const int n_vec4 = out_size / 4;                 // 16384*4096/4 = 16,777,216
    const int block  = 256;
    const int grid   = (n_vec4 + block - 1) / block; // 65536

    ControlFlowScanDecomposition_151564_46308337386065_kernel
        <<<grid, block, 0, stream>>>(img, pos, out);
}